// Round 2
// baseline (661.283 us; speedup 1.0000x reference)
//
#include <hip/hip_runtime.h>
#include <hip/hip_bf16.h>
#include <stdint.h>

// Problem constants: B=4, S=2048, IN=OUT=4096, R=16, SCALING=2.0
#define M_DIM 8192   // B*S
#define N_DIM 4096   // OUT
#define K_DIM 4096   // IN
#define R_DIM 16
#define NT    64     // K_DIM / 64 K-tiles

#define WROWS    32
#define WBLOCKS  (N_DIM / WROWS)   // 128 W-prep blocks, 32 rows each
#define CAST_BLOCKS 4096           // 2048 float4 per block

typedef __attribute__((ext_vector_type(8))) short bf16x8;   // A/B frag (4 VGPRs)
typedef __attribute__((ext_vector_type(4))) float f32x4;    // C/D frag

__device__ __forceinline__ unsigned short f2bf(float f) {
  union { float f; unsigned int u; } v; v.f = f;
  unsigned int r = 0x7FFFu + ((v.u >> 16) & 1u);   // RNE
  return (unsigned short)((v.u + r) >> 16);
}

__device__ __forceinline__ void gload16(const unsigned short* g, unsigned short* l) {
  __builtin_amdgcn_global_load_lds(
      (const __attribute__((address_space(1))) void*)g,
      (__attribute__((address_space(3))) void*)l,
      16, 0, 0);
}

// ---- prep ----
// blocks [0, WBLOCKS): W' = W + 2*(B@A) for 32 rows/block, A column-stationary
//   in registers (16 float4 loaded once per chunk, reused across 32 rows).
//   A L2 traffic: 128 blocks x 256 KB = 33 MB (was 1 GiB -> L2 hot-bank stall).
//   Bo (B row scaled) in LDS, broadcast reads (conflict-free).
// blocks [WBLOCKS, +4096): cast x fp32->bf16, 8 coalesced float4/thread.
__global__ void __launch_bounds__(256) prep_kernel(
    const float4* __restrict__ x4, ushort4* __restrict__ xbf4,
    const float4* __restrict__ W4, const float4* __restrict__ Aw4,
    const float* __restrict__ Bw, const float* __restrict__ mag,
    ushort4* __restrict__ wbf4, float* __restrict__ scale) {
  const int tid = threadIdx.x;
  __shared__ float BoL[WROWS * R_DIM];   // 2 KB
  __shared__ float red[4][WROWS];

  if (blockIdx.x >= WBLOCKS) {
    const int base = (blockIdx.x - WBLOCKS) * 2048 + tid;
    #pragma unroll
    for (int u = 0; u < 8; ++u) {
      const int i = base + u * 256;
      float4 f = x4[i];
      ushort4 o;
      o.x = f2bf(f.x); o.y = f2bf(f.y); o.z = f2bf(f.z); o.w = f2bf(f.w);
      xbf4[i] = o;
    }
    return;
  }

  const int o0 = blockIdx.x * WROWS;
  for (int i = tid; i < WROWS * R_DIM; i += 256)
    BoL[i] = Bw[o0 * R_DIM + i] * 2.0f;           // fold SCALING
  __syncthreads();

  float ssa[WROWS];
  #pragma unroll
  for (int r = 0; r < WROWS; ++r) ssa[r] = 0.f;

  for (int ch = 0; ch < 4; ++ch) {
    const int c = ch * 256 + tid;                 // float4 column, coalesced
    float4 a[R_DIM];
    #pragma unroll
    for (int r = 0; r < R_DIM; ++r) a[r] = Aw4[(size_t)r * 1024 + c];

    #pragma unroll
    for (int row = 0; row < WROWS; ++row) {
      float4 v = W4[(size_t)(o0 + row) * 1024 + c];
      const float4 b0 = *(const float4*)&BoL[row * R_DIM + 0];
      const float4 b1 = *(const float4*)&BoL[row * R_DIM + 4];
      const float4 b2 = *(const float4*)&BoL[row * R_DIM + 8];
      const float4 b3 = *(const float4*)&BoL[row * R_DIM + 12];
#define FMA4(bb, ar) { v.x += (bb)*(ar).x; v.y += (bb)*(ar).y; v.z += (bb)*(ar).z; v.w += (bb)*(ar).w; }
      FMA4(b0.x, a[0])  FMA4(b0.y, a[1])  FMA4(b0.z, a[2])  FMA4(b0.w, a[3])
      FMA4(b1.x, a[4])  FMA4(b1.y, a[5])  FMA4(b1.z, a[6])  FMA4(b1.w, a[7])
      FMA4(b2.x, a[8])  FMA4(b2.y, a[9])  FMA4(b2.z, a[10]) FMA4(b2.w, a[11])
      FMA4(b3.x, a[12]) FMA4(b3.y, a[13]) FMA4(b3.z, a[14]) FMA4(b3.w, a[15])
#undef FMA4
      ssa[row] += v.x * v.x + v.y * v.y + v.z * v.z + v.w * v.w;
      ushort4 ov;
      ov.x = f2bf(v.x); ov.y = f2bf(v.y); ov.z = f2bf(v.z); ov.w = f2bf(v.w);
      wbf4[(size_t)(o0 + row) * 1024 + c] = ov;
    }
  }

  const int lane = tid & 63;
  const int wave = tid >> 6;
  #pragma unroll
  for (int row = 0; row < WROWS; ++row) {
    float v = ssa[row];
    #pragma unroll
    for (int off = 32; off > 0; off >>= 1) v += __shfl_down(v, off, 64);
    if (lane == 0) red[wave][row] = v;
  }
  __syncthreads();
  if (tid < WROWS) {
    const float s = red[0][tid] + red[1][tid] + red[2][tid] + red[3][tid];
    scale[o0 + tid] = mag[o0 + tid] / sqrtf(s);
  }
}

// ------------- GEMM: C[m,n] = scale[n] * sum_k A[m,k]*Bt[n,k] -------------
// 256x256 tile, BK=64, 8 waves (2M x 4N), 512 threads, 8-phase schedule.
// LDS 128 KiB: A/B each 2(dbuf) x 2(half) x 128x64 bf16.
// Deep-prefetch slots (R1): GROUP(t) stages tile t+2 into its own buffer cc:
//   P2: Ah0(t+2)  (Ah0(t) last read P1)
//   P3: Bh0(t+2)  (Bh0(t) last read P1)
//   P4: Ah1(t+2)+Bh1(t+2)  (Ah1 last read P3, Bh1 last read P2)
// Waits (FIFO-simulated, steady state enters each GROUP with 12 outstanding):
//   P1-end vmcnt(8)  -> drains Ah1(t),Bh1(t), issued 5 phases earlier
//   P4-end vmcnt(12) -> drains Ah0(t+1),Bh0(t+1), issued 6 phases earlier
// Tail: G(NT-2): no stage, waits 8/4; G(NT-1): no stage, waits 0/0.
// Source-swizzle (l&7)^(l>>3); reads ((h*4+fq)^(fr&7)) -> conflict-free (R0: 0).
#define VMCNT_(n) asm volatile("s_waitcnt vmcnt(" #n ")" ::: "memory")
#define VMCNT(n) VMCNT_(n)

__global__ void __launch_bounds__(512, 2)
dora_gemm(const unsigned short* __restrict__ A,   // [M,K] bf16
          const unsigned short* __restrict__ Bt,  // [N,K] bf16
          const float* __restrict__ scale,        // [N]
          float* __restrict__ C) {                // [M,N] fp32
  __shared__ __align__(16) unsigned short As[2][2][128 * 64];
  __shared__ __align__(16) unsigned short Bs[2][2][128 * 64];

  const int tid  = threadIdx.x;
  const int lane = tid & 63;
  const int wave = tid >> 6;

  // T1: XCD-aware bijective swizzle (512 wgs, 512 % 8 == 0); 4x16 panel/XCD.
  const int fid = blockIdx.y * gridDim.x + blockIdx.x;
  const int s   = (fid & 7) * 64 + (fid >> 3);
  const int bM  = (s >> 4) * 256;
  const int bN  = (s & 15) * 256;

  const int l3  = lane >> 3;
  const int l7  = lane & 7;
  const int swz = (l7 ^ l3) * 8;        // pre-swizzled source col (shorts)
  const int w8  = wave * 8;

  const unsigned short* srcA = A  + (size_t)(bM + w8 + l3) * K_DIM + swz;
  const unsigned short* srcB = Bt + (size_t)(bN + (wave & 3) * 8 + l3 + 64 * (wave >> 2)) * K_DIM + swz;

  const int fr   = lane & 15;
  const int fq   = lane >> 4;
  const int fr7  = fr & 7;
  const int arow = fr + 64 * (wave >> 2);   // + mt*16
  const int brow = fr + 32 * (wave & 3);    // + nt*16

  f32x4 acc[8][4];
  #pragma unroll
  for (int i = 0; i < 8; ++i)
    #pragma unroll
    for (int j = 0; j < 4; ++j) acc[i][j] = (f32x4){0.f, 0.f, 0.f, 0.f};

  bf16x8 aF[4][2];      // current m-half A frags
  bf16x8 bF0[2][2];     // n-half 0 B frags (read P1, used P1+P3)
  bf16x8 bF1[2][2];     // n-half 1 B frags (read P2, used P2+P4)

#define STAGE_A(cc, hh, k0) do {                                              \
    gload16(srcA + (size_t)((hh) * 64)       * K_DIM + (k0), (unsigned short*)&As[cc][hh][w8 * 64]);        \
    gload16(srcA + (size_t)((hh) * 64 + 128) * K_DIM + (k0), (unsigned short*)&As[cc][hh][(64 + w8) * 64]); \
  } while (0)
#define STAGE_B(cc, hh, k0) do {                                              \
    gload16(srcB + (size_t)((hh) * 32)       * K_DIM + (k0), (unsigned short*)&Bs[cc][hh][w8 * 64]);        \
    gload16(srcB + (size_t)((hh) * 32 + 128) * K_DIM + (k0), (unsigned short*)&Bs[cc][hh][(64 + w8) * 64]); \
  } while (0)
#define LOAD_A(cc, mh) do {                                                   \
    _Pragma("unroll")                                                         \
    for (int mt = 0; mt < 4; ++mt) {                                          \
      _Pragma("unroll")                                                       \
      for (int h = 0; h < 2; ++h)                                             \
        aF[mt][h] = *(const bf16x8*)&As[cc][mh][(arow + mt * 16) * 64 + (((h * 4 + fq) ^ fr7) * 8)]; \
    }                                                                         \
  } while (0)
#define LOAD_B(cc, nh, dst) do {                                              \
    _Pragma("unroll")                                                         \
    for (int nt = 0; nt < 2; ++nt) {                                          \
      _Pragma("unroll")                                                       \
      for (int h = 0; h < 2; ++h)                                             \
        dst[nt][h] = *(const bf16x8*)&Bs[cc][nh][(brow + nt * 16) * 64 + (((h * 4 + fq) ^ fr7) * 8)]; \
    }                                                                         \
  } while (0)
#define MFMA_Q(mh, nh, bfr) do {                                              \
    _Pragma("unroll")                                                         \
    for (int mt = 0; mt < 4; ++mt) {                                          \
      _Pragma("unroll")                                                       \
      for (int nt = 0; nt < 2; ++nt) {                                        \
        _Pragma("unroll")                                                     \
        for (int h = 0; h < 2; ++h)                                           \
          acc[(mh) * 4 + mt][(nh) * 2 + nt] = __builtin_amdgcn_mfma_f32_16x16x32_bf16( \
              aF[mt][h], bfr[nt][h], acc[(mh) * 4 + mt][(nh) * 2 + nt], 0, 0, 0); \
      }                                                                       \
    }                                                                         \
  } while (0)
#define PH_SYNC_IN()  do { __builtin_amdgcn_s_barrier();                      \
    asm volatile("s_waitcnt lgkmcnt(0)" ::: "memory"); } while (0)
#define PRIO1 __builtin_amdgcn_s_setprio(1)
#define PRIO0 __builtin_amdgcn_s_setprio(0)

// STG: 1 = stage tile tt+2 into buffer cc. W1N/W4N: vmcnt at P1-end / P4-end.
#define GROUP(cc, tt, STG, W1N, W4N) do {                                     \
    /* P1 */                                                                  \
    LOAD_A(cc, 0); LOAD_B(cc, 0, bF0);                                        \
    PH_SYNC_IN();                                                             \
    PRIO1; MFMA_Q(0, 0, bF0); PRIO0;                                          \
    VMCNT(W1N);                                                               \
    __builtin_amdgcn_s_barrier();                                             \
    /* P2 */                                                                  \
    LOAD_B(cc, 1, bF1);                                                       \
    if (STG) STAGE_A(cc, 0, ((tt) + 2) * 64);                                 \
    PH_SYNC_IN();                                                             \
    PRIO1; MFMA_Q(0, 1, bF1); PRIO0;                                          \
    __builtin_amdgcn_s_barrier();                                             \
    /* P3 */                                                                  \
    LOAD_A(cc, 1);                                                            \
    if (STG) STAGE_B(cc, 0, ((tt) + 2) * 64);                                 \
    PH_SYNC_IN();                                                             \
    PRIO1; MFMA_Q(1, 0, bF0); PRIO0;                                          \
    __builtin_amdgcn_s_barrier();                                             \
    /* P4 */                                                                  \
    if (STG) { STAGE_A(cc, 1, ((tt) + 2) * 64); STAGE_B(cc, 1, ((tt) + 2) * 64); } \
    PH_SYNC_IN();                                                             \
    PRIO1; MFMA_Q(1, 1, bF1); PRIO0;                                          \
    VMCNT(W4N);                                                               \
    __builtin_amdgcn_s_barrier();                                             \
  } while (0)

  // prologue: stage tiles 0,1 fully (16 loads), drain the first half-tile pair
  STAGE_A(0, 0, 0);  STAGE_B(0, 0, 0);
  STAGE_A(0, 1, 0);  STAGE_B(0, 1, 0);
  STAGE_A(1, 0, 64); STAGE_B(1, 0, 64);
  STAGE_A(1, 1, 64); STAGE_B(1, 1, 64);
  VMCNT(12);
  __builtin_amdgcn_s_barrier();

  for (int t = 0; t < NT - 2; t += 2) {
    GROUP(0, t, 1, 8, 12);
    GROUP(1, t + 1, 1, 8, 12);
  }
  GROUP(0, NT - 2, 0, 8, 4);
  GROUP(1, NT - 1, 0, 0, 0);

#undef GROUP
#undef PRIO0
#undef PRIO1
#undef PH_SYNC_IN
#undef MFMA_Q
#undef LOAD_B
#undef LOAD_A
#undef STAGE_B
#undef STAGE_A

  // epilogue: C/D layout col=lane&15, row=(lane>>4)*4+reg  [m89]
  const int wMo = (wave >> 2) * 128;
  const int wNo = (wave & 3) * 64;
  float scv[4];
  #pragma unroll
  for (int fn = 0; fn < 4; ++fn) scv[fn] = scale[bN + wNo + fn * 16 + fr];
  #pragma unroll
  for (int fm = 0; fm < 8; ++fm) {
    const int m0 = bM + wMo + fm * 16 + fq * 4;
    #pragma unroll
    for (int fn = 0; fn < 4; ++fn) {
      const int n = bN + wNo + fn * 16 + fr;
      #pragma unroll
      for (int r = 0; r < 4; ++r)
        C[(size_t)(m0 + r) * N_DIM + n] = acc[fm][fn][r] * scv[fn];
    }
  }
}

extern "C" void kernel_launch(void* const* d_in, const int* in_sizes, int n_in,
                              void* d_out, int out_size, void* d_ws, size_t ws_size,
                              hipStream_t stream) {
  const float* x   = (const float*)d_in[0];   // [4,2048,4096]
  const float* W   = (const float*)d_in[1];   // [4096,4096]
  const float* la  = (const float*)d_in[2];   // [16,4096]
  const float* lb  = (const float*)d_in[3];   // [4096,16]
  const float* mag = (const float*)d_in[4];   // [4096]
  float* out = (float*)d_out;

  // ws: x_bf16 (64 MiB) | w_bf16 (32 MiB) | scale (16 KiB)
  unsigned short* xbf = (unsigned short*)d_ws;
  unsigned short* wbf = (unsigned short*)((char*)d_ws + (size_t)M_DIM * K_DIM * 2);
  float* scale = (float*)((char*)d_ws + (size_t)M_DIM * K_DIM * 2 + (size_t)N_DIM * K_DIM * 2);

  prep_kernel<<<WBLOCKS + CAST_BLOCKS, 256, 0, stream>>>(
      (const float4*)x, (ushort4*)xbf, (const float4*)W, (const float4*)la,
      lb, mag, (ushort4*)wbf, scale);
  dim3 grid(N_DIM / 256, M_DIM / 256);
  dora_gemm<<<grid, 512, 0, stream>>>(xbf, wbf, scale, out);
}

// Round 4
// 556.976 us; speedup vs baseline: 1.1873x; 1.1873x over previous
//
#include <hip/hip_runtime.h>
#include <hip/hip_bf16.h>
#include <stdint.h>

// Problem constants: B=4, S=2048, IN=OUT=4096, R=16, SCALING=2.0
#define M_DIM 8192   // B*S
#define N_DIM 4096   // OUT
#define K_DIM 4096   // IN
#define R_DIM 16
#define NT    64     // K_DIM / 64 K-tiles

#define WROWS    8
#define WBLOCKS  (N_DIM / WROWS)   // 512 W-prep blocks, 8 rows each
#define CAST_BLOCKS 4096           // 2048 float4 per block

typedef __attribute__((ext_vector_type(8))) short bf16x8;   // A/B frag (4 VGPRs)
typedef __attribute__((ext_vector_type(4))) float f32x4;    // C/D frag

__device__ __forceinline__ unsigned short f2bf(float f) {
  union { float f; unsigned int u; } v; v.f = f;
  unsigned int r = 0x7FFFu + ((v.u >> 16) & 1u);   // RNE
  return (unsigned short)((v.u + r) >> 16);
}

__device__ __forceinline__ void gload16(const unsigned short* g, unsigned short* l) {
  __builtin_amdgcn_global_load_lds(
      (const __attribute__((address_space(1))) void*)g,
      (__attribute__((address_space(3))) void*)l,
      16, 0, 0);
}

// ---- prep ----
// blocks [0, WBLOCKS): W' = W + 2*(B@A), 8 rows/block. A column-stationary in
//   regs (16 float4 per chunk, reused across 8 rows; ~110 VGPR, no spill).
//   A L2 traffic: 512 x 256KB = 128MB (L2-resident, ~4us).
// blocks [WBLOCKS, +4096): cast x fp32->bf16, 8 coalesced float4/thread.
__global__ void __launch_bounds__(256) prep_kernel(
    const float4* __restrict__ x4, ushort4* __restrict__ xbf4,
    const float4* __restrict__ W4, const float4* __restrict__ Aw4,
    const float* __restrict__ Bw, const float* __restrict__ mag,
    ushort4* __restrict__ wbf4, float* __restrict__ scale) {
  const int tid = threadIdx.x;
  __shared__ float BoL[WROWS * R_DIM];   // 512 B
  __shared__ float red[4][WROWS];

  if (blockIdx.x >= WBLOCKS) {
    const int base = (blockIdx.x - WBLOCKS) * 2048 + tid;
    #pragma unroll
    for (int u = 0; u < 8; ++u) {
      const int i = base + u * 256;
      float4 f = x4[i];
      ushort4 o;
      o.x = f2bf(f.x); o.y = f2bf(f.y); o.z = f2bf(f.z); o.w = f2bf(f.w);
      xbf4[i] = o;
    }
    return;
  }

  const int o0 = blockIdx.x * WROWS;
  if (tid < WROWS * R_DIM) BoL[tid] = Bw[o0 * R_DIM + tid] * 2.0f;  // fold SCALING
  __syncthreads();

  float ssa[WROWS];
  #pragma unroll
  for (int r = 0; r < WROWS; ++r) ssa[r] = 0.f;

  #pragma unroll 1
  for (int ch = 0; ch < 4; ++ch) {
    const int c = ch * 256 + tid;                 // float4 column, coalesced
    float4 a[R_DIM];
    #pragma unroll
    for (int r = 0; r < R_DIM; ++r) a[r] = Aw4[(size_t)r * 1024 + c];

    #pragma unroll
    for (int row = 0; row < WROWS; ++row) {
      float4 v = W4[(size_t)(o0 + row) * 1024 + c];
      const float4 b0 = *(const float4*)&BoL[row * R_DIM + 0];
      const float4 b1 = *(const float4*)&BoL[row * R_DIM + 4];
      const float4 b2 = *(const float4*)&BoL[row * R_DIM + 8];
      const float4 b3 = *(const float4*)&BoL[row * R_DIM + 12];
#define FMA4(bb, ar) { v.x += (bb)*(ar).x; v.y += (bb)*(ar).y; v.z += (bb)*(ar).z; v.w += (bb)*(ar).w; }
      FMA4(b0.x, a[0])  FMA4(b0.y, a[1])  FMA4(b0.z, a[2])  FMA4(b0.w, a[3])
      FMA4(b1.x, a[4])  FMA4(b1.y, a[5])  FMA4(b1.z, a[6])  FMA4(b1.w, a[7])
      FMA4(b2.x, a[8])  FMA4(b2.y, a[9])  FMA4(b2.z, a[10]) FMA4(b2.w, a[11])
      FMA4(b3.x, a[12]) FMA4(b3.y, a[13]) FMA4(b3.z, a[14]) FMA4(b3.w, a[15])
#undef FMA4
      ssa[row] += v.x * v.x + v.y * v.y + v.z * v.z + v.w * v.w;
      ushort4 ov;
      ov.x = f2bf(v.x); ov.y = f2bf(v.y); ov.z = f2bf(v.z); ov.w = f2bf(v.w);
      wbf4[(size_t)(o0 + row) * 1024 + c] = ov;
    }
  }

  const int lane = tid & 63;
  const int wave = tid >> 6;
  #pragma unroll
  for (int row = 0; row < WROWS; ++row) {
    float v = ssa[row];
    #pragma unroll
    for (int off = 32; off > 0; off >>= 1) v += __shfl_down(v, off, 64);
    if (lane == 0) red[wave][row] = v;
  }
  __syncthreads();
  if (tid < WROWS) {
    const float s = red[0][tid] + red[1][tid] + red[2][tid] + red[3][tid];
    scale[o0 + tid] = mag[o0 + tid] / sqrtf(s);
  }
}

// ------------- GEMM: C[m,n] = scale[n] * sum_k A[m,k]*Bt[n,k] -------------
// 256x256 tile, BK=64, 8 waves, 512 threads. 8-phase schedule, R3 variant:
// quadrant order Q00 -> Q01 -> Q11 -> Q10 makes each operand's two uses
// ADJACENT, so every fragment ds_read can be issued one phase early, placed
// (program-order) AFTER the MFMA cluster that last reads its registers --
// WAR dependencies give correctness; barriers bound the regions; the
// compiler's counted-lgkm insertion does the waits. ds_read latency is then
// covered by MFMA instead of alternating with it (old lockstep ceiling 62%).
//   P1: Q00(Ah0,Bh0)           ; issue bF1(t)
//   P2: Q01(Ah0,Bh1)+stage Ah0 ; roll-issue Ah1(t) (aLo after mt01, aHi after)
//   P3: Q11(Ah1,Bh1)+stage Bh0 ; vmcnt(W3) drains t+1
//   P4: Q10(Ah1,Bh0)+stage Ah1,Bh1 ; issue Ah0,Bh0(t+1) from buffer cc^1
// Stage slot WAR proofs + vmcnt FIFO (steady: enter 8, +2,+2 -> vmcnt(4)
// drains t+1's 8, +4 -> exit 8) re-verified. Source-swizzle (l&7)^(l>>3);
// reads ((h*4+fq)^(fr&7)) -> conflict-free (R1/R2: 0 conflicts).
#define VMCNT_(n) asm volatile("s_waitcnt vmcnt(" #n ")" ::: "memory")
#define VMCNT(n) VMCNT_(n)

__global__ void __launch_bounds__(512, 2)
dora_gemm(const unsigned short* __restrict__ A,   // [M,K] bf16
          const unsigned short* __restrict__ Bt,  // [N,K] bf16
          const float* __restrict__ scale,        // [N]
          float* __restrict__ C) {                // [M,N] fp32
  __shared__ __align__(16) unsigned short As[2][2][128 * 64];
  __shared__ __align__(16) unsigned short Bs[2][2][128 * 64];

  const int tid  = threadIdx.x;
  const int lane = tid & 63;
  const int wave = tid >> 6;

  // T1: XCD-aware bijective swizzle (512 wgs, 512 % 8 == 0); 4x16 panel/XCD.
  const int fid = blockIdx.y * gridDim.x + blockIdx.x;
  const int s   = (fid & 7) * 64 + (fid >> 3);
  const int bM  = (s >> 4) * 256;
  const int bN  = (s & 15) * 256;

  const int l3  = lane >> 3;
  const int l7  = lane & 7;
  const int swz = (l7 ^ l3) * 8;        // pre-swizzled source col (shorts)
  const int w8  = wave * 8;

  const unsigned short* srcA = A  + (size_t)(bM + w8 + l3) * K_DIM + swz;
  const unsigned short* srcB = Bt + (size_t)(bN + (wave & 3) * 8 + l3 + 64 * (wave >> 2)) * K_DIM + swz;

  const int fr   = lane & 15;
  const int fq   = lane >> 4;
  const int fr7  = fr & 7;
  const int arow = fr + 64 * (wave >> 2);   // + mt*16
  const int brow = fr + 32 * (wave & 3);    // + nt*16

  f32x4 acc[8][4];
  #pragma unroll
  for (int i = 0; i < 8; ++i)
    #pragma unroll
    for (int j = 0; j < 4; ++j) acc[i][j] = (f32x4){0.f, 0.f, 0.f, 0.f};

  bf16x8 aLo[2][2], aHi[2][2];  // A frags, mt 0-1 / 2-3 (rolling reload)
  bf16x8 bF0[2][2];             // Bh0 frags (used P1 + P4)
  bf16x8 bF1[2][2];             // Bh1 frags (used P2 + P3)

#define STAGE_A(cc, hh, k0) do {                                              \
    gload16(srcA + (size_t)((hh) * 64)       * K_DIM + (k0), (unsigned short*)&As[cc][hh][w8 * 64]);        \
    gload16(srcA + (size_t)((hh) * 64 + 128) * K_DIM + (k0), (unsigned short*)&As[cc][hh][(64 + w8) * 64]); \
  } while (0)
#define STAGE_B(cc, hh, k0) do {                                              \
    gload16(srcB + (size_t)((hh) * 32)       * K_DIM + (k0), (unsigned short*)&Bs[cc][hh][w8 * 64]);        \
    gload16(srcB + (size_t)((hh) * 32 + 128) * K_DIM + (k0), (unsigned short*)&Bs[cc][hh][(64 + w8) * 64]); \
  } while (0)
#define LOAD_A_LO(cc, mh) do {                                                \
    _Pragma("unroll")                                                         \
    for (int mi = 0; mi < 2; ++mi)                                            \
      _Pragma("unroll")                                                       \
      for (int h = 0; h < 2; ++h)                                             \
        aLo[mi][h] = *(const bf16x8*)&As[cc][mh][(arow + mi * 16) * 64 + (((h * 4 + fq) ^ fr7) * 8)]; \
  } while (0)
#define LOAD_A_HI(cc, mh) do {                                                \
    _Pragma("unroll")                                                         \
    for (int mi = 0; mi < 2; ++mi)                                            \
      _Pragma("unroll")                                                       \
      for (int h = 0; h < 2; ++h)                                             \
        aHi[mi][h] = *(const bf16x8*)&As[cc][mh][(arow + (mi + 2) * 16) * 64 + (((h * 4 + fq) ^ fr7) * 8)]; \
  } while (0)
#define LOAD_B(cc, nh, dst) do {                                              \
    _Pragma("unroll")                                                         \
    for (int nt = 0; nt < 2; ++nt) {                                          \
      _Pragma("unroll")                                                       \
      for (int h = 0; h < 2; ++h)                                             \
        dst[nt][h] = *(const bf16x8*)&Bs[cc][nh][(brow + nt * 16) * 64 + (((h * 4 + fq) ^ fr7) * 8)]; \
    }                                                                         \
  } while (0)
// 8 MFMAs: C-quadrant (mh,nh), A mt-pair {mtb,mtb+1} from aARR, B from bfr.
#define MFMA_PAIR(mh, nh, bfr, aARR, mtb) do {                                \
    _Pragma("unroll")                                                         \
    for (int mi = 0; mi < 2; ++mi) {                                          \
      _Pragma("unroll")                                                       \
      for (int nt = 0; nt < 2; ++nt) {                                        \
        _Pragma("unroll")                                                     \
        for (int h = 0; h < 2; ++h)                                           \
          acc[(mh) * 4 + (mtb) + mi][(nh) * 2 + nt] = __builtin_amdgcn_mfma_f32_16x16x32_bf16( \
              aARR[mi][h], bfr[nt][h], acc[(mh) * 4 + (mtb) + mi][(nh) * 2 + nt], 0, 0, 0); \
      }                                                                       \
    }                                                                         \
  } while (0)
#define BAR   __builtin_amdgcn_s_barrier()
#define PRIO1 __builtin_amdgcn_s_setprio(1)
#define PRIO0 __builtin_amdgcn_s_setprio(0)

// STG: stage tile tt+2 into buffer cc. W3: vmcnt at P3-end. NX: prefetch
// next tile's Ah0/Bh0 frags from buffer cc^1 during P4.
#define GROUP(cc, tt, STG, W3, NX) do {                                       \
    /* P1: Q00 (Ah0 x Bh0); issue bF1(t) */                                   \
    LOAD_B(cc, 1, bF1);                                                       \
    PRIO1; MFMA_PAIR(0, 0, bF0, aLo, 0); MFMA_PAIR(0, 0, bF0, aHi, 2); PRIO0; \
    BAR;                                                                      \
    /* P2: Q01 (Ah0 x Bh1); stage Ah0(t+2); roll-issue Ah1(t) */              \
    if (STG) STAGE_A(cc, 0, ((tt) + 2) * 64);                                 \
    PRIO1; MFMA_PAIR(0, 1, bF1, aLo, 0); PRIO0;                               \
    LOAD_A_LO(cc, 1);                                                         \
    PRIO1; MFMA_PAIR(0, 1, bF1, aHi, 2); PRIO0;                               \
    LOAD_A_HI(cc, 1);                                                         \
    BAR;                                                                      \
    /* P3: Q11 (Ah1 x Bh1); stage Bh0(t+2); drain t+1 */                      \
    if (STG) STAGE_B(cc, 0, ((tt) + 2) * 64);                                 \
    PRIO1; MFMA_PAIR(1, 1, bF1, aLo, 0); MFMA_PAIR(1, 1, bF1, aHi, 2); PRIO0; \
    VMCNT(W3);                                                                \
    BAR;                                                                      \
    /* P4: Q10 (Ah1 x Bh0); stage Ah1+Bh1(t+2); issue next Ah0+Bh0 */         \
    if (STG) { STAGE_A(cc, 1, ((tt) + 2) * 64); STAGE_B(cc, 1, ((tt) + 2) * 64); } \
    PRIO1; MFMA_PAIR(1, 0, bF0, aLo, 0); PRIO0;                               \
    if (NX) LOAD_A_LO((cc) ^ 1, 0);                                           \
    PRIO1; MFMA_PAIR(1, 0, bF0, aHi, 2); PRIO0;                               \
    if (NX) { LOAD_A_HI((cc) ^ 1, 0); LOAD_B((cc) ^ 1, 0, bF0); }             \
    BAR;                                                                      \
  } while (0)

  // prologue: stage tiles 0,1 fully; wait tile 0; issue G0's Ah0/Bh0 frags
  STAGE_A(0, 0, 0);  STAGE_B(0, 0, 0);
  STAGE_A(0, 1, 0);  STAGE_B(0, 1, 0);
  STAGE_A(1, 0, 64); STAGE_B(1, 0, 64);
  STAGE_A(1, 1, 64); STAGE_B(1, 1, 64);
  VMCNT(8);
  BAR;
  LOAD_A_LO(0, 0); LOAD_A_HI(0, 0); LOAD_B(0, 0, bF0);

  for (int t = 0; t < NT - 2; t += 2) {
    GROUP(0, t,     1, 4, 1);
    GROUP(1, t + 1, 1, 4, 1);
  }
  GROUP(0, NT - 2, 0, 0, 1);
  GROUP(1, NT - 1, 0, 0, 0);

#undef GROUP
#undef PRIO0
#undef PRIO1
#undef BAR
#undef MFMA_PAIR
#undef LOAD_B
#undef LOAD_A_HI
#undef LOAD_A_LO
#undef STAGE_B
#undef STAGE_A

  // epilogue: C/D layout col=lane&15, row=(lane>>4)*4+reg  [m89]
  const int wMo = (wave >> 2) * 128;
  const int wNo = (wave & 3) * 64;
  float scv[4];
  #pragma unroll
  for (int fn = 0; fn < 4; ++fn) scv[fn] = scale[bN + wNo + fn * 16 + fr];
  #pragma unroll
  for (int fm = 0; fm < 8; ++fm) {
    const int m0 = bM + wMo + fm * 16 + fq * 4;
    #pragma unroll
    for (int fn = 0; fn < 4; ++fn) {
      const int n = bN + wNo + fn * 16 + fr;
      #pragma unroll
      for (int r = 0; r < 4; ++r)
        C[(size_t)(m0 + r) * N_DIM + n] = acc[fm][fn][r] * scv[fn];
    }
  }
}

extern "C" void kernel_launch(void* const* d_in, const int* in_sizes, int n_in,
                              void* d_out, int out_size, void* d_ws, size_t ws_size,
                              hipStream_t stream) {
  const float* x   = (const float*)d_in[0];   // [4,2048,4096]
  const float* W   = (const float*)d_in[1];   // [4096,4096]
  const float* la  = (const float*)d_in[2];   // [16,4096]
  const float* lb  = (const float*)d_in[3];   // [4096,16]
  const float* mag = (const float*)d_in[4];   // [4096]
  float* out = (float*)d_out;

  // ws: x_bf16 (64 MiB) | w_bf16 (32 MiB) | scale (16 KiB)
  unsigned short* xbf = (unsigned short*)d_ws;
  unsigned short* wbf = (unsigned short*)((char*)d_ws + (size_t)M_DIM * K_DIM * 2);
  float* scale = (float*)((char*)d_ws + (size_t)M_DIM * K_DIM * 2 + (size_t)N_DIM * K_DIM * 2);

  prep_kernel<<<WBLOCKS + CAST_BLOCKS, 256, 0, stream>>>(
      (const float4*)x, (ushort4*)xbf, (const float4*)W, (const float4*)la,
      lb, mag, (ushort4*)wbf, scale);
  dim3 grid(N_DIM / 256, M_DIM / 256);
  dora_gemm<<<grid, 512, 0, stream>>>(xbf, wbf, scale, out);
}

// Round 5
// 532.004 us; speedup vs baseline: 1.2430x; 1.0469x over previous
//
#include <hip/hip_runtime.h>
#include <hip/hip_bf16.h>
#include <stdint.h>

// Problem constants: B=4, S=2048, IN=OUT=4096, R=16, SCALING=2.0
#define M_DIM 8192   // B*S
#define N_DIM 4096   // OUT
#define K_DIM 4096   // IN
#define R_DIM 16
#define NT    64     // K_DIM / 64 K-tiles

#define CAST_BLOCKS 4096           // 2048 float4 per block

typedef __attribute__((ext_vector_type(8))) short bf16x8;   // A/B frag (4 VGPRs)
typedef __attribute__((ext_vector_type(4))) float f32x4;    // C/D frag

__device__ __forceinline__ unsigned short f2bf(float f) {
  union { float f; unsigned int u; } v; v.f = f;
  unsigned int r = 0x7FFFu + ((v.u >> 16) & 1u);   // RNE
  return (unsigned short)((v.u + r) >> 16);
}

__device__ __forceinline__ void gload16(const unsigned short* g, unsigned short* l) {
  __builtin_amdgcn_global_load_lds(
      (const __attribute__((address_space(1))) void*)g,
      (__attribute__((address_space(3))) void*)l,
      16, 0, 0);
}

// ---- prep, split for rocprof visibility (R4 post-mortem: residual ~311us
// never attributed; separate dispatch names let the slow path surface) ----

// cast x fp32->bf16: 4096 blocks, 8 coalesced float4/thread. ~31us roofline.
__global__ void __launch_bounds__(256) prep_cast(
    const float4* __restrict__ x4, ushort4* __restrict__ xbf4) {
  const int base = blockIdx.x * 2048 + threadIdx.x;
  #pragma unroll
  for (int u = 0; u < 8; ++u) {
    const int i = base + u * 256;
    float4 f = x4[i];
    ushort4 o;
    o.x = f2bf(f.x); o.y = f2bf(f.y); o.z = f2bf(f.z); o.w = f2bf(f.w);
    xbf4[i] = o;
  }
}

// W' = W + 2*(B@A), row norm, scale; one W-row per block (4096 blocks).
// REVERT to R1-measured-best structure: Bo[16] scalar regs, no big arrays,
// zero spill risk. (Column-stationary variants R2/R4 were SLOWER: 384/311
// vs 267 residual -- L2-amplification theory refuted by measurement.)
__global__ void __launch_bounds__(256) prep_w(
    const float4* __restrict__ W4, const float4* __restrict__ Aw4,
    const float* __restrict__ Bw, const float* __restrict__ mag,
    ushort4* __restrict__ wbf4, float* __restrict__ scale) {
  const int tid = threadIdx.x;
  const int o = blockIdx.x;
  float Bo[R_DIM];
  #pragma unroll
  for (int r = 0; r < R_DIM; ++r) Bo[r] = Bw[o * R_DIM + r] * 2.0f;  // fold SCALING

  float ss = 0.f;
  #pragma unroll
  for (int g = 0; g < 4; ++g) {
    const int c = g * 256 + tid;                  // float4 column, coalesced
    float4 v = W4[(size_t)o * 1024 + c];
    #pragma unroll
    for (int r = 0; r < R_DIM; ++r) {
      const float4 a = Aw4[(size_t)r * 1024 + c];
      const float b = Bo[r];
      v.x += b * a.x; v.y += b * a.y; v.z += b * a.z; v.w += b * a.w;
    }
    ss += v.x * v.x + v.y * v.y + v.z * v.z + v.w * v.w;
    ushort4 ov;
    ov.x = f2bf(v.x); ov.y = f2bf(v.y); ov.z = f2bf(v.z); ov.w = f2bf(v.w);
    wbf4[(size_t)o * 1024 + c] = ov;
  }

  __shared__ float red[4];
  #pragma unroll
  for (int off = 32; off > 0; off >>= 1) ss += __shfl_down(ss, off, 64);
  if ((tid & 63) == 0) red[tid >> 6] = ss;
  __syncthreads();
  if (tid == 0)
    scale[o] = mag[o] / sqrtf(red[0] + red[1] + red[2] + red[3]);
}

// ------------- GEMM: C[m,n] = scale[n] * sum_k A[m,k]*Bt[n,k] -------------
// 256x256 tile, BK=64, 8 waves, 512 threads. 8-phase schedule, R3 variant
// (UNCHANGED from R4: measured 246us / 1117 TF / MfmaUtil 49% / 0 conflicts):
// quadrant order Q00 -> Q01 -> Q11 -> Q10 makes each operand's two uses
// ADJACENT, so every fragment ds_read is issued one phase early, placed
// after the MFMA cluster that last reads its registers (WAR-correct,
// barrier-bounded, compiler-counted lgkm waits).
//   P1: Q00(Ah0,Bh0)           ; issue bF1(t)
//   P2: Q01(Ah0,Bh1)+stage Ah0 ; roll-issue Ah1(t)
//   P3: Q11(Ah1,Bh1)+stage Bh0 ; vmcnt(W3) drains t+1
//   P4: Q10(Ah1,Bh0)+stage Ah1,Bh1 ; issue Ah0,Bh0(t+1) from buffer cc^1
// Source-swizzle (l&7)^(l>>3); reads ((h*4+fq)^(fr&7)) -> conflict-free.
#define VMCNT_(n) asm volatile("s_waitcnt vmcnt(" #n ")" ::: "memory")
#define VMCNT(n) VMCNT_(n)

__global__ void __launch_bounds__(512, 2)
dora_gemm(const unsigned short* __restrict__ A,   // [M,K] bf16
          const unsigned short* __restrict__ Bt,  // [N,K] bf16
          const float* __restrict__ scale,        // [N]
          float* __restrict__ C) {                // [M,N] fp32
  __shared__ __align__(16) unsigned short As[2][2][128 * 64];
  __shared__ __align__(16) unsigned short Bs[2][2][128 * 64];

  const int tid  = threadIdx.x;
  const int lane = tid & 63;
  const int wave = tid >> 6;

  // T1: XCD-aware bijective swizzle (512 wgs, 512 % 8 == 0); 4x16 panel/XCD.
  const int fid = blockIdx.y * gridDim.x + blockIdx.x;
  const int s   = (fid & 7) * 64 + (fid >> 3);
  const int bM  = (s >> 4) * 256;
  const int bN  = (s & 15) * 256;

  const int l3  = lane >> 3;
  const int l7  = lane & 7;
  const int swz = (l7 ^ l3) * 8;        // pre-swizzled source col (shorts)
  const int w8  = wave * 8;

  const unsigned short* srcA = A  + (size_t)(bM + w8 + l3) * K_DIM + swz;
  const unsigned short* srcB = Bt + (size_t)(bN + (wave & 3) * 8 + l3 + 64 * (wave >> 2)) * K_DIM + swz;

  const int fr   = lane & 15;
  const int fq   = lane >> 4;
  const int fr7  = fr & 7;
  const int arow = fr + 64 * (wave >> 2);   // + mt*16
  const int brow = fr + 32 * (wave & 3);    // + nt*16

  f32x4 acc[8][4];
  #pragma unroll
  for (int i = 0; i < 8; ++i)
    #pragma unroll
    for (int j = 0; j < 4; ++j) acc[i][j] = (f32x4){0.f, 0.f, 0.f, 0.f};

  bf16x8 aLo[2][2], aHi[2][2];  // A frags, mt 0-1 / 2-3 (rolling reload)
  bf16x8 bF0[2][2];             // Bh0 frags (used P1 + P4)
  bf16x8 bF1[2][2];             // Bh1 frags (used P2 + P3)

#define STAGE_A(cc, hh, k0) do {                                              \
    gload16(srcA + (size_t)((hh) * 64)       * K_DIM + (k0), (unsigned short*)&As[cc][hh][w8 * 64]);        \
    gload16(srcA + (size_t)((hh) * 64 + 128) * K_DIM + (k0), (unsigned short*)&As[cc][hh][(64 + w8) * 64]); \
  } while (0)
#define STAGE_B(cc, hh, k0) do {                                              \
    gload16(srcB + (size_t)((hh) * 32)       * K_DIM + (k0), (unsigned short*)&Bs[cc][hh][w8 * 64]);        \
    gload16(srcB + (size_t)((hh) * 32 + 128) * K_DIM + (k0), (unsigned short*)&Bs[cc][hh][(64 + w8) * 64]); \
  } while (0)
#define LOAD_A_LO(cc, mh) do {                                                \
    _Pragma("unroll")                                                         \
    for (int mi = 0; mi < 2; ++mi)                                            \
      _Pragma("unroll")                                                       \
      for (int h = 0; h < 2; ++h)                                             \
        aLo[mi][h] = *(const bf16x8*)&As[cc][mh][(arow + mi * 16) * 64 + (((h * 4 + fq) ^ fr7) * 8)]; \
  } while (0)
#define LOAD_A_HI(cc, mh) do {                                                \
    _Pragma("unroll")                                                         \
    for (int mi = 0; mi < 2; ++mi)                                            \
      _Pragma("unroll")                                                       \
      for (int h = 0; h < 2; ++h)                                             \
        aHi[mi][h] = *(const bf16x8*)&As[cc][mh][(arow + (mi + 2) * 16) * 64 + (((h * 4 + fq) ^ fr7) * 8)]; \
  } while (0)
#define LOAD_B(cc, nh, dst) do {                                              \
    _Pragma("unroll")                                                         \
    for (int nt = 0; nt < 2; ++nt) {                                          \
      _Pragma("unroll")                                                       \
      for (int h = 0; h < 2; ++h)                                             \
        dst[nt][h] = *(const bf16x8*)&Bs[cc][nh][(brow + nt * 16) * 64 + (((h * 4 + fq) ^ fr7) * 8)]; \
    }                                                                         \
  } while (0)
// 8 MFMAs: C-quadrant (mh,nh), A mt-pair {mtb,mtb+1} from aARR, B from bfr.
#define MFMA_PAIR(mh, nh, bfr, aARR, mtb) do {                                \
    _Pragma("unroll")                                                         \
    for (int mi = 0; mi < 2; ++mi) {                                          \
      _Pragma("unroll")                                                       \
      for (int nt = 0; nt < 2; ++nt) {                                        \
        _Pragma("unroll")                                                     \
        for (int h = 0; h < 2; ++h)                                           \
          acc[(mh) * 4 + (mtb) + mi][(nh) * 2 + nt] = __builtin_amdgcn_mfma_f32_16x16x32_bf16( \
              aARR[mi][h], bfr[nt][h], acc[(mh) * 4 + (mtb) + mi][(nh) * 2 + nt], 0, 0, 0); \
      }                                                                       \
    }                                                                         \
  } while (0)
#define BAR   __builtin_amdgcn_s_barrier()
#define PRIO1 __builtin_amdgcn_s_setprio(1)
#define PRIO0 __builtin_amdgcn_s_setprio(0)

// STG: stage tile tt+2 into buffer cc. W3: vmcnt at P3-end. NX: prefetch
// next tile's Ah0/Bh0 frags from buffer cc^1 during P4.
#define GROUP(cc, tt, STG, W3, NX) do {                                       \
    /* P1: Q00 (Ah0 x Bh0); issue bF1(t) */                                   \
    LOAD_B(cc, 1, bF1);                                                       \
    PRIO1; MFMA_PAIR(0, 0, bF0, aLo, 0); MFMA_PAIR(0, 0, bF0, aHi, 2); PRIO0; \
    BAR;                                                                      \
    /* P2: Q01 (Ah0 x Bh1); stage Ah0(t+2); roll-issue Ah1(t) */              \
    if (STG) STAGE_A(cc, 0, ((tt) + 2) * 64);                                 \
    PRIO1; MFMA_PAIR(0, 1, bF1, aLo, 0); PRIO0;                               \
    LOAD_A_LO(cc, 1);                                                         \
    PRIO1; MFMA_PAIR(0, 1, bF1, aHi, 2); PRIO0;                               \
    LOAD_A_HI(cc, 1);                                                         \
    BAR;                                                                      \
    /* P3: Q11 (Ah1 x Bh1); stage Bh0(t+2); drain t+1 */                      \
    if (STG) STAGE_B(cc, 0, ((tt) + 2) * 64);                                 \
    PRIO1; MFMA_PAIR(1, 1, bF1, aLo, 0); MFMA_PAIR(1, 1, bF1, aHi, 2); PRIO0; \
    VMCNT(W3);                                                                \
    BAR;                                                                      \
    /* P4: Q10 (Ah1 x Bh0); stage Ah1+Bh1(t+2); issue next Ah0+Bh0 */         \
    if (STG) { STAGE_A(cc, 1, ((tt) + 2) * 64); STAGE_B(cc, 1, ((tt) + 2) * 64); } \
    PRIO1; MFMA_PAIR(1, 0, bF0, aLo, 0); PRIO0;                               \
    if (NX) LOAD_A_LO((cc) ^ 1, 0);                                           \
    PRIO1; MFMA_PAIR(1, 0, bF0, aHi, 2); PRIO0;                               \
    if (NX) { LOAD_A_HI((cc) ^ 1, 0); LOAD_B((cc) ^ 1, 0, bF0); }             \
    BAR;                                                                      \
  } while (0)

  // prologue: stage tiles 0,1 fully; wait tile 0; issue G0's Ah0/Bh0 frags
  STAGE_A(0, 0, 0);  STAGE_B(0, 0, 0);
  STAGE_A(0, 1, 0);  STAGE_B(0, 1, 0);
  STAGE_A(1, 0, 64); STAGE_B(1, 0, 64);
  STAGE_A(1, 1, 64); STAGE_B(1, 1, 64);
  VMCNT(8);
  BAR;
  LOAD_A_LO(0, 0); LOAD_A_HI(0, 0); LOAD_B(0, 0, bF0);

  for (int t = 0; t < NT - 2; t += 2) {
    GROUP(0, t,     1, 4, 1);
    GROUP(1, t + 1, 1, 4, 1);
  }
  GROUP(0, NT - 2, 0, 0, 1);
  GROUP(1, NT - 1, 0, 0, 0);

#undef GROUP
#undef PRIO0
#undef PRIO1
#undef BAR
#undef MFMA_PAIR
#undef LOAD_B
#undef LOAD_A_HI
#undef LOAD_A_LO
#undef STAGE_B
#undef STAGE_A

  // epilogue: C/D layout col=lane&15, row=(lane>>4)*4+reg  [m89]
  const int wMo = (wave >> 2) * 128;
  const int wNo = (wave & 3) * 64;
  float scv[4];
  #pragma unroll
  for (int fn = 0; fn < 4; ++fn) scv[fn] = scale[bN + wNo + fn * 16 + fr];
  #pragma unroll
  for (int fm = 0; fm < 8; ++fm) {
    const int m0 = bM + wMo + fm * 16 + fq * 4;
    #pragma unroll
    for (int fn = 0; fn < 4; ++fn) {
      const int n = bN + wNo + fn * 16 + fr;
      #pragma unroll
      for (int r = 0; r < 4; ++r)
        C[(size_t)(m0 + r) * N_DIM + n] = acc[fm][fn][r] * scv[fn];
    }
  }
}

extern "C" void kernel_launch(void* const* d_in, const int* in_sizes, int n_in,
                              void* d_out, int out_size, void* d_ws, size_t ws_size,
                              hipStream_t stream) {
  const float* x   = (const float*)d_in[0];   // [4,2048,4096]
  const float* W   = (const float*)d_in[1];   // [4096,4096]
  const float* la  = (const float*)d_in[2];   // [16,4096]
  const float* lb  = (const float*)d_in[3];   // [4096,16]
  const float* mag = (const float*)d_in[4];   // [4096]
  float* out = (float*)d_out;

  // ws: x_bf16 (64 MiB) | w_bf16 (32 MiB) | scale (16 KiB)
  unsigned short* xbf = (unsigned short*)d_ws;
  unsigned short* wbf = (unsigned short*)((char*)d_ws + (size_t)M_DIM * K_DIM * 2);
  float* scale = (float*)((char*)d_ws + (size_t)M_DIM * K_DIM * 2 + (size_t)N_DIM * K_DIM * 2);

  prep_w<<<N_DIM, 256, 0, stream>>>(
      (const float4*)W, (const float4*)la, lb, mag, (ushort4*)wbf, scale);
  prep_cast<<<CAST_BLOCKS, 256, 0, stream>>>(
      (const float4*)x, (ushort4*)xbf);
  dim3 grid(N_DIM / 256, M_DIM / 256);
  dora_gemm<<<grid, 512, 0, stream>>>(xbf, wbf, scale, out);
}